// Round 28
// baseline (173.937 us; speedup 1.0000x reference)
//
#include <hip/hip_runtime.h>
#include <float.h>

#define NPIX 16384    // B*H*W pixels
#define NE   8192     // codebook entries
#define KD   256      // channels
#define HW   1024
#define BCHW 262144
#define NT   8        // N-tiles (128 codes) per wg -> wg spans 1024 codes (slice)
#define DELTA 2.5e-4f // rescue window: bf16 err + 2x key quant + margin
#define KMASK 0xFFFFE000u

typedef __attribute__((ext_vector_type(8))) short short8;
typedef __attribute__((ext_vector_type(4))) short short4v;
typedef __attribute__((ext_vector_type(4))) float f32x4;
typedef __attribute__((ext_vector_type(4))) unsigned int u32x4;
typedef unsigned long long u64;
typedef unsigned int u32;

__device__ __forceinline__ u32 fkey(float f) {
    u32 u = __float_as_uint(f);
    return u ^ ((u >> 31) ? 0xFFFFFFFFu : 0x80000000u);
}
__device__ __forceinline__ short bf16rne(float f) {
    u32 u = __float_as_uint(f);
    u += 0x7FFFu + ((u >> 16) & 1u);
    return (short)(u >> 16);
}
__device__ __forceinline__ float kval(u32 pk) {   // packed key -> quantized value
    return __uint_as_float(pk & KMASK);
}

#define GLDS(gp, lp) __builtin_amdgcn_global_load_lds( \
    (const __attribute__((address_space(1))) void*)(gp), \
    (__attribute__((address_space(3))) void*)(lp), 16, 0, 0)

// ---------------------------------------------------------------------------
// FUSED prep: blocks [0,2048): codebook -> bf16 + e2 (one wave per row);
//             blocks [2048,3072): z [b][k][hw] fp32 -> zh [p][k] bf16.
// ---------------------------------------------------------------------------
__global__ __launch_bounds__(256) void vq_prep2(
    const float* __restrict__ cb, const float* __restrict__ z,
    short* __restrict__ eh, float* __restrict__ e2, short* __restrict__ zh)
{
    __shared__ float ts[64][65];
    const int tid = threadIdx.x;

    if (blockIdx.x < 2048) {
        const int row  = ((int)blockIdx.x * 256 + tid) >> 6;
        const int lane = tid & 63;
        const f32x4 v = *(const f32x4*)(cb + (size_t)row * KD + lane * 4);
        short4v h;
        h[0] = bf16rne(v[0]); h[1] = bf16rne(v[1]);
        h[2] = bf16rne(v[2]); h[3] = bf16rne(v[3]);
        *(short4v*)(eh + (size_t)row * KD + lane * 4) = h;
        float s = v[0]*v[0] + v[1]*v[1] + v[2]*v[2] + v[3]*v[3];
        #pragma unroll
        for (int m = 1; m < 64; m <<= 1) s += __shfl_xor(s, m);
        if (lane == 0) e2[row] = s;
    } else {
        const int bid = (int)blockIdx.x - 2048;      // 0..1023
        const int hw0 = (bid & 15) * 64;
        const int k0  = ((bid >> 4) & 3) * 64;
        const int b   = bid >> 6;
        const int pl  = tid & 63, kk = tid >> 6;
        #pragma unroll
        for (int i = 0; i < 16; ++i) {
            const int k = kk + 4 * i;
            ts[k][pl] = z[b * BCHW + (k0 + k) * HW + hw0 + pl];
        }
        __syncthreads();
        const int tx = tid & 15, ty = tid >> 4;
        #pragma unroll
        for (int j = 0; j < 4; ++j) {
            const int p = ty + 16 * j;
            short4v v;
            #pragma unroll
            for (int q = 0; q < 4; ++q) v[q] = bf16rne(ts[tx * 4 + q][p]);
            *(short4v*)(zh + (size_t)(b * HW + hw0 + p) * KD + k0 + tx * 4) = v;
        }
    }
}

// ---------------------------------------------------------------------------
// Fused GEMM + per-(pixel, HALF-slice) top-4 tracking.
// R28: B-fragment SOFTWARE PIPELINE (1-step lag). At step s: barrier(tile s)
// -> stage(s+2) -> ds_read tile s into bfv[s&1] -> MFMA tile s-1 from
// bfv[(s-1)&1] (reads issued a full step earlier => no lgkm wait on the
// MFMA critical path). Barrier/stage/vmcnt structure identical to R24.
// All buffer/fragment indices compile-time static. Epilogue computes
// tile 63. Merge for slice nt-1 happens at (nt, t==0).
// ---------------------------------------------------------------------------
__global__ __launch_bounds__(512, 2) void vq_gemm(
    const short* __restrict__ zh, const short* __restrict__ eh,
    u32* __restrict__ best4)
{
    __shared__ short Bs[4][4096];   // [buf][128 rows x 32 k]  (32 KB)

    const int tid  = threadIdx.x;
    const int lane = tid & 63;
    const int w    = tid >> 6;          // 0..7
    const int wm   = w >> 1, wn = w & 1;
    const int lr   = lane & 15;
    const int p0   = blockIdx.x * 128;
    const int nb0  = blockIdx.y * (NT * 128);

    const int sr = lane >> 2;           // 0..15 row in wave's 16-row block
    const int ss = (lane & 3) ^ ((sr >> 1) & 3);
    const int q   = lane >> 4;
    const int rsw = (lr >> 1) & 3;

    u32 b1[2][4], b2[2][4];
    #pragma unroll
    for (int m = 0; m < 2; ++m)
        #pragma unroll
        for (int r = 0; r < 4; ++r) { b1[m][r] = 0xFFFFFFFFu; b2[m][r] = 0xFFFFFFFFu; }

    // ---- A-fragments: direct global -> register, once per wg ----
    short8 afr[2][8];
    #pragma unroll
    for (int m = 0; m < 2; ++m) {
        const size_t rowb = (size_t)(p0 + wm * 32 + m * 16 + lr) * KD;
        #pragma unroll
        for (int ks = 0; ks < 8; ++ks)
            afr[m][ks] = *(const short8*)(zh + rowb + ks * 32 + q * 8);
    }
    asm volatile("s_waitcnt vmcnt(0)" ::: "memory");

    #define STAGEB(nt_, t_, buf_) do {                                         \
        const int k0_ = (t_) * 32;                                             \
        const int n0_ = nb0 + (nt_) * 128;                                     \
        GLDS(eh + (size_t)(n0_ + w * 16 + sr) * KD + k0_ + ss * 8,             \
             &Bs[buf_][w * 512]);                                              \
    } while (0)

    // read B frags of buffer buf_ into bfv[reg_]
    #define READB(buf_, reg_) do {                                             \
        _Pragma("unroll")                                                      \
        for (int nf_ = 0; nf_ < 4; ++nf_) {                                    \
            const int row_ = wn * 64 + nf_ * 16 + lr;                          \
            bfv[reg_][nf_] =                                                   \
                *(const short8*)&Bs[buf_][row_ * 32 + ((q ^ rsw) * 8)];        \
        }                                                                      \
    } while (0)

    // 8 MFMAs for compute-substep tc_ using bfv[reg_]
    #define DOMFMA(tc_, reg_) do {                                             \
        __builtin_amdgcn_s_setprio(1);                                         \
        _Pragma("unroll")                                                      \
        for (int m_ = 0; m_ < 2; ++m_)                                         \
            _Pragma("unroll")                                                  \
            for (int nf_ = 0; nf_ < 4; ++nf_)                                  \
                acc[m_][nf_] = __builtin_amdgcn_mfma_f32_16x16x32_bf16(        \
                    afr[m_][tc_], bfv[reg_][nf_], acc[m_][nf_], 0, 0, 0);      \
        __builtin_amdgcn_s_setprio(0);                                         \
    } while (0)

    // register-only best-2 merge for slice ntc_
    #define MERGE(ntc_) do {                                                   \
        const u32 nbase = (u32)(nb0 + (ntc_) * 128 + wn * 64 + lr);            \
        _Pragma("unroll")                                                      \
        for (int m_ = 0; m_ < 2; ++m_) {                                       \
            _Pragma("unroll")                                                  \
            for (int r_ = 0; r_ < 4; ++r_) {                                   \
                u32 pk0 = (__float_as_uint(0.0625f - acc[m_][0][r_]) & KMASK) | (nbase);        \
                u32 pk1 = (__float_as_uint(0.0625f - acc[m_][1][r_]) & KMASK) | (nbase + 16u);  \
                u32 pk2 = (__float_as_uint(0.0625f - acc[m_][2][r_]) & KMASK) | (nbase + 32u);  \
                u32 pk3 = (__float_as_uint(0.0625f - acc[m_][3][r_]) & KMASK) | (nbase + 48u);  \
                const u32 lo01 = min(pk0, pk1), hi01 = max(pk0, pk1);          \
                const u32 lo23 = min(pk2, pk3), hi23 = max(pk2, pk3);          \
                const u32 m1 = min(lo01, lo23);                                \
                const u32 m2 = min(max(lo01, lo23), min(hi01, hi23));          \
                const u32 nb1 = min(b1[m_][r_], m1);                           \
                const u32 nb2 = min(max(b1[m_][r_], m1), min(b2[m_][r_], m2)); \
                b1[m_][r_] = nb1; b2[m_][r_] = nb2;                            \
            }                                                                  \
        }                                                                      \
    } while (0)

    #define ZEROACC() do {                                                     \
        _Pragma("unroll")                                                      \
        for (int m_ = 0; m_ < 2; ++m_)                                         \
            _Pragma("unroll")                                                  \
            for (int nf_ = 0; nf_ < 4; ++nf_)                                  \
                acc[m_][nf_] = (f32x4){0.f, 0.f, 0.f, 0.f};                    \
    } while (0)

    f32x4 acc[2][4];
    short8 bfv[2][4];

    STAGEB(0, 0, 0);
    STAGEB(0, 1, 1);

    #pragma unroll 1
    for (int nt = 0; nt < NT; ++nt) {
        const bool lastnt = (nt == NT - 1);
        #pragma unroll
        for (int t = 0; t < 8; ++t) {
            // tile s = nt*8+t: own GLDS landed; newer (s+1) stays in flight
            if (lastnt && t == 7) asm volatile("s_waitcnt vmcnt(0)" ::: "memory");
            else                  asm volatile("s_waitcnt vmcnt(1)" ::: "memory");
            __builtin_amdgcn_sched_barrier(0);
            __builtin_amdgcn_s_barrier();   // tile s visible to all waves

            if (t < 6)        { STAGEB(nt, t + 2, (t + 2) & 3); }
            else if (!lastnt) { STAGEB(nt + 1, t - 6, (t - 6) & 3); }

            // read tile s = (nt,t) into bfv[t&1]  (consumed next step)
            READB(t & 3, t & 1);

            // compute tile s-1 = (nt, t-1) or (nt-1, 7)
            if (t == 0) {
                if (nt > 0) {
                    DOMFMA(7, 1);          // (nt-1, t_c=7), bfv[(8nt-1)&1]=1
                    MERGE(nt - 1);
                }
            } else {
                if (t == 1) ZEROACC();     // t_c = 0: new slice accumulator
                DOMFMA(t - 1, (t - 1) & 1);
            }
        }
    }
    #undef STAGEB

    // epilogue: compute tile 63 (nt=7, t_c=7) and merge slice 7
    DOMFMA(7, 1);
    MERGE(7);
    #undef READB
    #undef DOMFMA
    #undef MERGE
    #undef ZEROACC

    // ---- wg-end: top-4 of this wave's lane-union per pixel ----
    const int g = lane >> 4;
    const int hs = blockIdx.y * 2 + wn;          // half-slice: single writer
    #pragma unroll
    for (int m = 0; m < 2; ++m) {
        #pragma unroll
        for (int r = 0; r < 4; ++r) {
            u32 a = b1[m][r], b = b2[m][r];
            u32 o[4];
            #pragma unroll
            for (int j = 0; j < 4; ++j) {
                u32 mm = a;
                #pragma unroll
                for (int msk = 1; msk < 16; msk <<= 1)
                    mm = min(mm, (u32)__shfl_xor((int)mm, msk));
                o[j] = mm;
                if (a == mm) { a = b; b = 0xFFFFFFFFu; }
            }
            if (lr == 0) {
                const int prow = p0 + wm * 32 + m * 16 + g * 4 + r;
                u32x4 ov; ov[0] = o[0]; ov[1] = o[1]; ov[2] = o[2]; ov[3] = o[3];
                *(u32x4*)&best4[((size_t)prow * 16 + hs) * 4] = ov;
            }
        }
    }
}

// ---------------------------------------------------------------------------
// FUSED exact + output: one wg per 32 pixels, 256 threads. (R25, unchanged)
// ---------------------------------------------------------------------------
__global__ __launch_bounds__(256) void vq_out_kernel(
    const float* __restrict__ z, const float* __restrict__ cb,
    const float* __restrict__ e2, const u32* __restrict__ best4,
    float* __restrict__ out, float* __restrict__ idxf,
    float* __restrict__ loss)
{
    __shared__ float zb[32][260];   // 33.3 KB  z block (exact dots + loss)
    __shared__ float zq[32][257];   // 32.9 KB  gathered codebook rows
    __shared__ u64  sfinal[32];
    __shared__ int  nidx[32];
    __shared__ u32  work[2048];     // (px<<13)|n  (hard cap 32*64)
    __shared__ u32  scans[512];     // (px<<4)|hs  (hard cap 32*16)
    __shared__ int  nwork, nscan;

    const int tid = threadIdx.x;
    const int p0  = blockIdx.x * 32;
    const int bb  = p0 >> 10, hw0 = p0 & 1023;

    if (tid == 0) { nwork = 0; nscan = 0; }
    if (tid < 32) sfinal[tid] = ~0ULL;
    __syncthreads();

    // Phase A ------------------------------------------------------------
    {
        const int pix = tid >> 3;          // 0..31
        const int hp  = (tid & 7) * 2;     // this thread's 2 half-slices
        const u32* src = &best4[((size_t)(p0 + pix) * 16 + hp) * 4];
        const u32x4 kv0 = *(const u32x4*)(src);
        const u32x4 kv1 = *(const u32x4*)(src + 4);
        u32 lmin = min(min(kv0[0], kv0[1]), min(kv0[2], kv0[3]));
        lmin = min(lmin, min(min(kv1[0], kv1[1]), min(kv1[2], kv1[3])));
        u32 mn = lmin;
        #pragma unroll
        for (int m = 1; m < 8; m <<= 1) mn = min(mn, (u32)__shfl_xor((int)mn, m));
        const float thr = kval(mn) + DELTA;
        int c8 = 0;
        #pragma unroll
        for (int j = 0; j < 4; ++j) c8 += (kval(kv0[j]) <= thr) ? 1 : 0;
        #pragma unroll
        for (int j = 0; j < 4; ++j) c8 += (kval(kv1[j]) <= thr) ? 1 : 0;
        int cnt = c8;
        #pragma unroll
        for (int m = 1; m < 8; m <<= 1) cnt += __shfl_xor(cnt, m);
        const int s0 = (kval(kv0[3]) <= thr) ? 1 : 0;
        const int s1 = (kval(kv1[3]) <= thr) ? 1 : 0;
        int anysusp = s0 + s1;
        #pragma unroll
        for (int m = 1; m < 8; m <<= 1) anysusp += __shfl_xor(anysusp, m);

        if (cnt == 1 && anysusp == 0) {
            if (lmin == mn) sfinal[pix] = (u64)(mn & 8191u);
        } else {
            if (c8 > 0) {
                const int base = atomicAdd(&nwork, c8);
                int k = 0;
                #pragma unroll
                for (int j = 0; j < 4; ++j)
                    if (kval(kv0[j]) <= thr)
                        work[base + (k++)] = ((u32)pix << 13) | (kv0[j] & 8191u);
                #pragma unroll
                for (int j = 0; j < 4; ++j)
                    if (kval(kv1[j]) <= thr)
                        work[base + (k++)] = ((u32)pix << 13) | (kv1[j] & 8191u);
            }
            if (s0) scans[atomicAdd(&nscan, 1)] = ((u32)pix << 4) | (u32)hp;
            if (s1) scans[atomicAdd(&nscan, 1)] = ((u32)pix << 4) | (u32)(hp + 1);
        }
    }
    __syncthreads();

    // Stage zb (always -- feeds exact dots AND the loss) -------------------
    #pragma unroll
    for (int i = 0; i < 32; ++i) {
        const int idx = i * 256 + tid;
        const int c = idx >> 5, px = idx & 31;
        zb[px][c] = z[(size_t)bb * BCHW + (size_t)c * HW + hw0 + px];
    }
    __syncthreads();

    const int nw = nwork, ns = nscan;

    // Phase C: one thread per passer candidate ----------------------------
    for (int i = tid; i < nw; i += 256) {
        const u32 e = work[i];
        const int px = (int)(e >> 13), n = (int)(e & 8191u);
        const float* er = cb + (size_t)n * KD;
        float acc = 0.f;
        #pragma unroll 4
        for (int k = 0; k < KD; k += 4) {
            const f32x4 zv = *(const f32x4*)&zb[px][k];
            const f32x4 ev = *(const f32x4*)(er + k);
            acc += zv[0]*ev[0] + zv[1]*ev[1] + zv[2]*ev[2] + zv[3]*ev[3];
        }
        const float s = 0.5f * e2[n] - acc;
        atomicMin(&sfinal[px], ((u64)fkey(s) << 32) | (u32)n);
    }

    // Phase D: suspect half-slice scans (rare) ----------------------------
    for (int si = 0; si < ns; ++si) {
        const u32 e = scans[si];
        const int px = (int)(e >> 4), hx = (int)(e & 15u);
        u64 bku = ~0ULL;
        #pragma unroll
        for (int h = 0; h < 2; ++h) {
            const int ci = tid + h * 256;
            const int n = (hx >> 1) * 1024 + (ci >> 6) * 128
                        + (hx & 1) * 64 + (ci & 63);
            const float* er = cb + (size_t)n * KD;
            float acc = 0.f;
            #pragma unroll 4
            for (int k = 0; k < KD; k += 4) {
                const f32x4 zv = *(const f32x4*)&zb[px][k];
                const f32x4 ev = *(const f32x4*)(er + k);
                acc += zv[0]*ev[0] + zv[1]*ev[1] + zv[2]*ev[2] + zv[3]*ev[3];
            }
            const float s = 0.5f * e2[n] - acc;
            const u64 pk = ((u64)fkey(s) << 32) | (u32)n;
            bku = min(bku, pk);
        }
        #pragma unroll
        for (int m = 1; m < 64; m <<= 1) {
            const u64 o = (u64)__shfl_xor((long long)bku, m);
            bku = min(bku, o);
        }
        if ((tid & 63) == 0) atomicMin(&sfinal[px], bku);
    }
    __syncthreads();

    // Winners -> idx output ------------------------------------------------
    if (tid < 32) {
        const int n = (int)((u32)sfinal[tid] & 8191u);
        nidx[tid] = n;
        idxf[p0 + tid] = (float)n;
    }
    __syncthreads();

    // Gather 32 codebook rows coalesced -----------------------------------
    {
        const int r = tid >> 3, i = tid & 7;
        const float* src = cb + (size_t)nidx[r] * KD;
        #pragma unroll
        for (int j = 0; j < 8; ++j) {
            const int col = i * 4 + j * 32;
            const f32x4 v = *(const f32x4*)(src + col);
            zq[r][col + 0] = v[0]; zq[r][col + 1] = v[1];
            zq[r][col + 2] = v[2]; zq[r][col + 3] = v[3];
        }
    }
    __syncthreads();

    // Channel-first z_q write + loss (z from zb) --------------------------
    const int p4 = (tid & 7) * 4;
    const int cg = tid >> 3;
    float ls = 0.f;
    #pragma unroll
    for (int ii = 0; ii < 8; ++ii) {
        const int c = cg + 32 * ii;
        const size_t e = (size_t)bb * BCHW + (size_t)c * HW + hw0 + p4;
        f32x4 v;
        v[0] = zq[p4 + 0][c]; v[1] = zq[p4 + 1][c];
        v[2] = zq[p4 + 2][c]; v[3] = zq[p4 + 3][c];
        *(f32x4*)(out + e) = v;
        const float d0 = v[0] - zb[p4 + 0][c], d1 = v[1] - zb[p4 + 1][c];
        const float d2 = v[2] - zb[p4 + 2][c], d3 = v[3] - zb[p4 + 3][c];
        ls += d0 * d0 + d1 * d1 + d2 * d2 + d3 * d3;
    }
    #pragma unroll
    for (int m = 1; m < 64; m <<= 1) ls += __shfl_xor(ls, m);
    if ((tid & 63) == 0) atomicAdd(loss, ls * (1.25f / 4194304.f));
}

// ---------------------------------------------------------------------------
extern "C" void kernel_launch(void* const* d_in, const int* in_sizes, int n_in,
                              void* d_out, int out_size, void* d_ws, size_t ws_size,
                              hipStream_t stream) {
    const float* z  = (const float*)d_in[0];
    const float* cb = (const float*)d_in[1];
    float* out  = (float*)d_out;
    float* idxf = out + 4194304;
    float* loss = out + 4210688;
    // scratch inside the z_q region of d_out (fully overwritten at the end):
    char* ob = (char*)d_out;
    short* zh    = (short*)ob;                    // [0 .. 8MB)   bf16 z [p][k]
    short* eh    = (short*)(ob + 8388608);        // [8 .. 12MB)  bf16 codebook
    u32*   best4 = (u32*)(ob + 12582912);         // [12 .. 16MB) 16384 x 16 x 4 u32

    float* e2 = (float*)d_ws;                // 32 KB

    hipMemsetAsync(loss, 0, 4, stream);

    vq_prep2<<<3072, 256, 0, stream>>>(cb, z, eh, e2, zh);
    vq_gemm<<<dim3(NPIX / 128, NE / (NT * 128)), 512, 0, stream>>>(zh, eh, best4);
    vq_out_kernel<<<NPIX / 32, 256, 0, stream>>>(z, cb, e2, best4, out, idxf, loss);
}